// Round 7
// baseline (16656.938 us; speedup 1.0000x reference)
//
#include <hip/hip_runtime.h>
#include <cmath>

#define L_     10
#define R_     64
#define G_     128
#define S_     256
#define MEL_   80
#define NCLS_  256
#define HOP_   64
#define END_   256
#define FRAMES_ 8
#define T_     512

// ---- workspace layout (float offsets) ----
#define COND8_OFF   0                               // 8*1280
#define HIST_OFF    10240                           // layers 1..8: [(j-1)][512][64]
#define MBX_OFF     (HIST_OFF + 8*T_*R_)            // [10][320]: mbx[j] = input to B_j (x 64 | skip 256)
#define MBSKIP_OFF  (MBX_OFF + 10*320)              // [256]
#define MBHID_OFF   (MBSKIP_OFF + 256)              // [256]
#define MBLOG_OFF   (MBHID_OFF + 256)               // [128]
#define FLAG_OFF    (MBLOG_OFF + 128)               // 16 flags, 16 ints apart (64B)

#define FID_SKIP   10
#define FID_HID0   11
#define FID_HID1   12
#define FID_LOG    13
#define FID_PREV   14
#define FID_CLAIM  15

#define NROLE 14
#define SPIN_CAP 4096

// ================= all-RMW comm primitives (XCD-0 pinned) =================
// Every cross-CU transfer is a RETURNING atomic (sc0 = return old value) that
// EXECUTES at the local TCC (XCD-0 L2, the coherence point for our pinned
// pipeline). The inline s_waitcnt vmcnt(0) after a returning atomic waits for
// the TCC's response, i.e. the op has committed in L2 — not merely been
// queued (the suspected flag-overtakes-data race of rounds 4-6). Atomics
// never hit L1 on CDNA, so consumer reads can never be stale either.
__device__ __forceinline__ void st_atomic_f(float* p, float v) {
  int old;
  asm volatile("global_atomic_swap %0, %1, %2, off sc0\n\ts_waitcnt vmcnt(0)"
               : "=&v"(old) : "v"(p), "v"(__float_as_int(v)) : "memory");
}
__device__ __forceinline__ float ld_atomic_f(const float* p) {
  int v;
  asm volatile("global_atomic_add %0, %1, %2, off sc0\n\ts_waitcnt vmcnt(0)"
               : "=&v"(v) : "v"(p), "v"(0) : "memory");
  return __int_as_float(v);
}
__device__ __forceinline__ void flag_store_atomic(int* p, int v) {
  int old;
  asm volatile("global_atomic_swap %0, %1, %2, off sc0\n\ts_waitcnt vmcnt(0)"
               : "=&v"(old) : "v"(p), "v"(v) : "memory");
}
__device__ __forceinline__ int flag_poll_atomic(int* p) {
  int v;
  asm volatile("global_atomic_add %0, %1, %2, off sc0\n\ts_waitcnt vmcnt(0)"
               : "=&v"(v) : "v"(p), "v"(0) : "memory");
  return v;
}
// whole-wave wait: lane 0 polls (one RMW per round), broadcasts via shfl.
__device__ __forceinline__ void wait_flag_wave(int* p, int want, int lane) {
  int v = 0, n = 0;
  do {
    if (lane == 0) v = flag_poll_atomic(p);
    v = __shfl(v, 0, 64);
    if (v >= want) break;
  } while (++n <= SPIN_CAP);
}
__device__ __forceinline__ int wait_prev_wave(int* p, int want, int lane) {
  int v = 0, n = 0;
  do {
    if (lane == 0) v = flag_poll_atomic(p);
    v = __shfl(v, 0, 64);
    if ((v >> 16) >= want) break;
  } while (++n <= SPIN_CAP);
  return v & 0xffff;
}

// ---- single-chain dot macros: EXACT round-2 arithmetic (absmax 0.0 proven).
// DO NOT restructure the fma chains: the sampling comparison cumsum > s*total
// sits on 1-ulp knife edges.
#define DOTREG(N4, W, V4, ACC) do { \
  _Pragma("unroll") \
  for (int k_ = 0; k_ < (N4); ++k_) { float4 a_ = (V4)[k_]; \
    ACC = fmaf((W)[4*k_+0], a_.x, ACC); ACC = fmaf((W)[4*k_+1], a_.y, ACC); \
    ACC = fmaf((W)[4*k_+2], a_.z, ACC); ACC = fmaf((W)[4*k_+3], a_.w, ACC); } \
} while (0)

#define DOTREG_RELU(N4, W, V4, ACC) do { \
  _Pragma("unroll") \
  for (int k_ = 0; k_ < (N4); ++k_) { float4 a_ = (V4)[k_]; \
    a_.x = fmaxf(a_.x, 0.f); a_.y = fmaxf(a_.y, 0.f); \
    a_.z = fmaxf(a_.z, 0.f); a_.w = fmaxf(a_.w, 0.f); \
    ACC = fmaf((W)[4*k_+0], a_.x, ACC); ACC = fmaf((W)[4*k_+1], a_.y, ACC); \
    ACC = fmaf((W)[4*k_+2], a_.z, ACC); ACC = fmaf((W)[4*k_+3], a_.w, ACC); } \
} while (0)

__global__ void cond_prep_kernel(const float* __restrict__ condW,
                                 const float* __restrict__ y,
                                 float* __restrict__ cond8) {
  int idx = blockIdx.x * blockDim.x + threadIdx.x;
  if (idx >= FRAMES_ * L_ * G_) return;
  int f = idx / (L_ * G_);
  int row = idx - f * (L_ * G_);
  float acc = 0.f;
  for (int m = 0; m < MEL_; ++m)
    acc = fmaf(condW[row * MEL_ + m], y[m * FRAMES_ + f], acc);
  cond8[f * (L_ * G_) + row] = acc;
}

__global__ __launch_bounds__(256, 1) void wavenet_pipe(
    const float* __restrict__ samples,
    const int*   __restrict__ c_ptr,
    const float* __restrict__ emb,
    const float* __restrict__ WVp,
    const float* __restrict__ WVx,
    const float* __restrict__ Wo,
    const float* __restrict__ Wob,
    const float* __restrict__ Wol,
    const float* __restrict__ Wobl,
    const float* __restrict__ e1w,
    const float* __restrict__ e1b,
    const float* __restrict__ e2w,
    const float* __restrict__ e2b,
    float* __restrict__ ws,
    int*   __restrict__ out) {

  const int tid = threadIdx.x;

  float* cond8  = ws + COND8_OFF;
  float* hist   = ws + HIST_OFF;
  float* mbx    = ws + MBX_OFF;
  float* mbskip = ws + MBSKIP_OFF;
  float* mbhid  = ws + MBHID_OFF;
  float* mblog  = ws + MBLOG_OFF;
  int*   flags  = (int*)(ws + FLAG_OFF);

  __shared__ __align__(16) float x_s[R_];
  __shared__ __align__(16) float past_s[R_];
  __shared__ __align__(16) float h_s[G_];
  __shared__ __align__(16) float z_s[R_];
  __shared__ __align__(16) float pd_s[G_];
  __shared__ __align__(16) float cond_s[FRAMES_ * G_];   // D1 reuses as logits
  __shared__ __align__(16) float vec_s[S_];              // skip / hid staging
  __shared__ float wred[4], wsum[4];
  __shared__ int wcand[4];
  __shared__ int role_s;

  // ---- XCD-pinned role claiming: only blocks on XCD 0 take a pipeline role.
  // 256 blocks -> XCD 0 hosts ~32 (round-robin dispatch); first NROLE claim a
  // role. All pipeline workers share XCD 0's TCC -> atomic comms coherent.
  {
    unsigned xcc;
    asm volatile("s_getreg_b32 %0, hwreg(HW_REG_XCC_ID)" : "=s"(xcc));
    if (tid == 0) {
      int r = -1;
      if (xcc == 0) {
        int c0 = atomicAdd(flags + FID_CLAIM * 16, 1);   // device-scope
        if (c0 < NROLE) r = c0;
      }
      role_s = r;
    }
    __syncthreads();
  }
  const int bid = role_s;
  if (bid < 0) return;

  if (bid < 10) {
    // ======================= layer stage B_j =======================
    const int j = bid;
    const int row = tid >> 1, half = tid & 1;
    const int dil = 1 << j;

    float wp[32], wx[32], wo0[64], wo1[64];
    float b0 = 0.f, b1 = 0.f;
    {
      const float* p = WVx + ((size_t)(j * G_ + row)) * R_ + half * 32;
      #pragma unroll
      for (int k = 0; k < 32; ++k) wx[k] = p[k];
    }
    if (j < 9) {
      const float* p = WVp + ((size_t)(j * G_ + row)) * R_ + half * 32;
      #pragma unroll
      for (int k = 0; k < 32; ++k) wp[k] = p[k];
      const float* q = Wo + ((size_t)(j * (R_ + S_) + tid)) * R_;
      #pragma unroll
      for (int k = 0; k < 64; ++k) wo0[k] = q[k];
      b0 = Wob[j * (R_ + S_) + tid];
      if (tid < 64) {
        const float* q2 = Wo + ((size_t)(j * (R_ + S_) + 256 + tid)) * R_;
        #pragma unroll
        for (int k = 0; k < 64; ++k) wo1[k] = q2[k];
        b1 = Wob[j * (R_ + S_) + 256 + tid];
      }
    } else {
      const float* q = Wol + (size_t)tid * R_;
      #pragma unroll
      for (int k = 0; k < 64; ++k) wo0[k] = q[k];
      b0 = Wobl[tid];
    }
    for (int i = tid; i < FRAMES_ * G_; i += 256)
      cond_s[i] = cond8[(i >> 7) * (L_ * G_) + j * G_ + (i & 127)];
    __syncthreads();
    if (tid < G_) pd_s[tid] = cond_s[tid];  // t=0: past term is 0, f=0

    const float* inx   = mbx + (size_t)j * 320;
    const float* insk  = mbx + (size_t)j * 320 + 64;
    float* outx  = (j < 9) ? (mbx + (size_t)(j + 1) * 320) : nullptr;
    float* outsk = (j < 9) ? (mbx + (size_t)(j + 1) * 320 + 64) : mbskip;
    int* inflag   = flags + j * 16;                  // valid for j>=1
    int* prevflag = flags + FID_PREV * 16;
    int* outflag  = (j < 9) ? (flags + (j + 1) * 16) : (flags + FID_SKIP * 16);
    float* myhist = (j >= 1 && j < 9) ? (hist + (size_t)(j - 1) * T_ * R_) : nullptr;

    for (int t = 0; t < T_; ++t) {
      // -- acquire input, stage x into LDS (wave 0 spins; others park at barrier)
      if (tid < 64) {
        if (j == 0) {
          int prev = 127;
          if (t > 0) prev = wait_prev_wave(prevflag, t, tid);
          if (tid < 16)
            ((float4*)x_s)[tid] = ((const float4*)(emb + (size_t)prev * R_))[tid];
        } else {
          wait_flag_wave(inflag, t + 1, tid);
          x_s[tid] = ld_atomic_f(inx + tid);     // fresh from TCC, 1 RMW/lane
        }
      }
      __syncthreads();

      // -- gates: h = pd_s (past-dot + cond, precomputed) + WVx @ x
      {
        float v = 0.f;
        const float4* xs4 = (const float4*)(x_s + half * 32);
        DOTREG(8, wx, xs4, v);
        v += __shfl_down(v, 1, 2);
        if (half == 0) h_s[row] = v + pd_s[row];
      }
      if (myhist && tid < 16)  // dilation ring write (same-CU consumer, plain)
        ((float4*)(myhist + (size_t)t * R_))[tid] = ((const float4*)x_s)[tid];
      __syncthreads();

      if (tid < 64) {
        float hw = h_s[tid], hf = h_s[tid + 64];
        z_s[tid] = tanhf(hw) * (1.f / (1.f + expf(-hf)));
      }
      __syncthreads();

      // -- W_o @ z, residual + skip accumulate, publish via returning swaps
      {
        float skin0 = 0.f, skin1 = 0.f;
        if (j > 0 && j < 9) {
          if (tid >= 64) skin0 = ld_atomic_f(insk + (tid - 64));
          else           skin1 = ld_atomic_f(insk + 192 + tid);
        }
        float v0 = 0.f;
        const float4* z4 = (const float4*)z_s;
        DOTREG(16, wo0, z4, v0);
        if (j < 9) {
          if (tid < 64) {
            float v1 = 0.f;
            DOTREG(16, wo1, z4, v1);
            st_atomic_f(outx + tid, x_s[tid] + v0 + b0);
            st_atomic_f(outsk + 192 + tid, skin1 + v1 + b1);
          } else {
            st_atomic_f(outsk + (tid - 64), skin0 + v0 + b0);
          }
        } else {
          float skin = ld_atomic_f(insk + tid);
          st_atomic_f(outsk + tid, skin + v0 + b0);
        }
      }
      __syncthreads();          // every lane's swap has EXECUTED at the TCC
      if (tid == 0) flag_store_atomic(outflag, t + 1);

      // -- off-critical-path: precompute past-dot + cond for t+1
      const int tn = t + 1;
      if (tn < T_) {
        const int f1 = tn >> 6;
        if (j == 0) {
          float v = 0.f;
          const float4* ps4 = (const float4*)(x_s + half * 32);  // past(t+1) = x(t)
          DOTREG(8, wp, ps4, v);
          v += __shfl_down(v, 1, 2);
          if (half == 0) pd_s[row] = v + cond_s[f1 * G_ + row];
        } else if (j < 9) {
          const int tp = tn - dil;
          if (tid < 16) {
            float4 pv = make_float4(0.f, 0.f, 0.f, 0.f);
            if (tp >= 0) pv = ((const float4*)(myhist + (size_t)tp * R_))[tid];
            ((float4*)past_s)[tid] = pv;
          }
          __syncthreads();
          float v = 0.f;
          const float4* ps4 = (const float4*)(past_s + half * 32);
          DOTREG(8, wp, ps4, v);
          v += __shfl_down(v, 1, 2);
          if (half == 0) pd_s[row] = v + cond_s[f1 * G_ + row];
        } else {
          if (tid < G_) pd_s[tid] = cond_s[f1 * G_ + tid];
        }
      }
      __syncthreads();  // pd_s/x_s fully written before next-iter overwrite
    }

  } else if (bid < 12) {
    // ======================= E1 stage C_h =======================
    const int h = bid - 10;
    const int o_loc = tid >> 1, halfc = tid & 1;
    float w[128];
    {
      const float* p = e1w + ((size_t)(h * 128 + o_loc)) * S_ + halfc * 128;
      #pragma unroll
      for (int k = 0; k < 128; ++k) w[k] = p[k];
    }
    const float bias = e1b[h * 128 + o_loc];
    int* inflag  = flags + FID_SKIP * 16;
    int* outflag = flags + ((h == 0) ? FID_HID0 : FID_HID1) * 16;
    float* outp = mbhid + h * 128;

    for (int t = 0; t < T_; ++t) {
      if (tid < 64) wait_flag_wave(inflag, t + 1, tid);
      __syncthreads();
      vec_s[tid] = ld_atomic_f(mbskip + tid);   // all 256 lanes, 1 RMW each
      __syncthreads();
      float v = 0.f;
      const float4* s4 = (const float4*)(vec_s + halfc * 128);
      DOTREG_RELU(32, w, s4, v);
      v += __shfl_down(v, 1, 2);
      if (halfc == 0) st_atomic_f(outp + o_loc, fmaxf(v + bias, 0.f));
      __syncthreads();
      if (tid == 0) flag_store_atomic(outflag, t + 1);
    }

  } else {
    // ======================= E2 stage D_h (D1 samples) =======================
    const int h = bid - 12;
    const int o_loc = tid >> 1, halfc = tid & 1;
    const float cf = (float)c_ptr[0];
    float w[128];
    {
      const float* p = e2w + ((size_t)(h * 128 + o_loc)) * END_ + halfc * 128;
      #pragma unroll
      for (int k = 0; k < 128; ++k) w[k] = p[k];
    }
    const float bias = e2b[h * 128 + o_loc];
    int* f0    = flags + FID_HID0 * 16;
    int* f1p   = flags + FID_HID1 * 16;
    int* flog  = flags + FID_LOG * 16;
    int* fprev = flags + FID_PREV * 16;
    float* logits_s = cond_s;  // reuse (unused by D stages)
    const int lane = tid & 63, wv = tid >> 6;

    for (int t = 0; t < T_; ++t) {
      if (tid < 64) {
        wait_flag_wave(f0, t + 1, tid);
        wait_flag_wave(f1p, t + 1, tid);
      }
      __syncthreads();
      vec_s[tid] = ld_atomic_f(mbhid + tid);    // all 256 lanes
      __syncthreads();
      float v = 0.f;
      const float4* h4 = (const float4*)(vec_s + halfc * 128);
      DOTREG(32, w, h4, v);
      v += __shfl_down(v, 1, 2);

      if (h == 0) {
        if (halfc == 0) st_atomic_f(mblog + o_loc, (v + bias) * cf);
        __syncthreads();
        if (tid == 0) flag_store_atomic(flog, t + 1);
      } else {
        if (halfc == 0) logits_s[128 + o_loc] = (v + bias) * cf;
        if (tid < 64) wait_flag_wave(flog, t + 1, tid);
        __syncthreads();
        if (tid < 128) logits_s[tid] = ld_atomic_f(mblog + tid);
        __syncthreads();

        // ---- softmax-CDF sampling over 256 logits (round-2 exact) ----
        float lg = logits_s[tid];
        float m = lg;
        #pragma unroll
        for (int off = 32; off >= 1; off >>= 1) m = fmaxf(m, __shfl_xor(m, off, 64));
        if (lane == 0) wred[wv] = m;
        __syncthreads();
        m = fmaxf(fmaxf(wred[0], wred[1]), fmaxf(wred[2], wred[3]));
        float e = expf(lg - m);
        float cs = e;
        #pragma unroll
        for (int off = 1; off < 64; off <<= 1) {
          float o_ = __shfl_up(cs, off, 64);
          if (lane >= off) cs += o_;
        }
        if (lane == 63) wsum[wv] = cs;
        __syncthreads();
        float total = wsum[0] + wsum[1] + wsum[2] + wsum[3];
        float offv = 0.f;
        for (int w2 = 0; w2 < wv; ++w2) offv += wsum[w2];
        float thresh = samples[t] * total;
        bool flagb = (offv + cs) > thresh;
        unsigned long long mk = __ballot(flagb);
        if (lane == 0) wcand[wv] = mk ? (wv * 64 + __ffsll(mk) - 1) : 100000;
        __syncthreads();
        if (tid == 0) {
          int nw = min(min(wcand[0], wcand[1]), min(wcand[2], wcand[3]));
          if (nw >= 100000) nw = 0;  // argmax of all-False -> 0
          out[t] = nw;
          flag_store_atomic(fprev, ((t + 1) << 16) | nw);
        }
        __syncthreads();  // protect wred/wsum/logits_s before next step
      }
    }
  }
}

extern "C" void kernel_launch(void* const* d_in, const int* in_sizes, int n_in,
                              void* d_out, int out_size, void* d_ws, size_t ws_size,
                              hipStream_t stream) {
  const float* y       = (const float*)d_in[0];
  const float* samples = (const float*)d_in[1];
  const int*   c       = (const int*)d_in[2];
  const float* emb     = (const float*)d_in[3];
  const float* condW   = (const float*)d_in[4];
  const float* WVp     = (const float*)d_in[5];
  const float* WVx     = (const float*)d_in[6];
  const float* Wo      = (const float*)d_in[7];
  const float* Wob     = (const float*)d_in[8];
  const float* Wol     = (const float*)d_in[9];
  const float* Wobl    = (const float*)d_in[10];
  const float* e1w     = (const float*)d_in[11];
  const float* e1b     = (const float*)d_in[12];
  const float* e2w     = (const float*)d_in[13];
  const float* e2b     = (const float*)d_in[14];

  float* ws  = (float*)d_ws;
  int*   out = (int*)d_out;

  // flags + claim counter must start at 0 every launch (ws re-poisoned to 0xAA)
  hipMemsetAsync((char*)d_ws + (size_t)FLAG_OFF * sizeof(float), 0,
                 16 * 16 * sizeof(int), stream);

  cond_prep_kernel<<<(FRAMES_ * L_ * G_ + 255) / 256, 256, 0, stream>>>(
      condW, y, ws + COND8_OFF);

  wavenet_pipe<<<256, 256, 0, stream>>>(samples, c, emb, WVp, WVx, Wo, Wob,
                                        Wol, Wobl, e1w, e1b, e2w, e2b, ws, out);
}

// Round 8
// 12713.835 us; speedup vs baseline: 1.3101x; 1.3101x over previous
//
#include <hip/hip_runtime.h>
#include <cmath>

#define L_     10
#define R_     64
#define G_     128
#define S_     256
#define MEL_   80
#define NCLS_  256
#define HOP_   64
#define END_   256
#define FRAMES_ 8
#define T_     512

// ---- workspace layout (float offsets) ----
#define COND8_OFF   0                                  // 8*1280
#define HIST_OFF    10240                              // rings layers 1..8: [(j-1)][512][64]
#define MBX_OFF     (HIST_OFF + 8*T_*R_)               // x mailboxes: [4][64]   (input to B1..B4)
#define MBSK_OFF    (MBX_OFF + 4*64)                   // skip mailboxes: [4][256]
#define MBSKIP_OFF  (MBSK_OFF + 4*256)                 // B4 -> C [256]
#define MBHID_OFF   (MBSKIP_OFF + 256)                 // C -> D [256]
#define FLAG_OFF    (MBHID_OFF + 256)                  // 16 flags, 16 ints apart

// flag ids: 1..4 = input flag of B1..B4
#define FID_SKIP   5
#define FID_HID    6
#define FID_PREV   7
#define FID_CLAIM  8

#define NROLE 7
#define SPIN_CAP (1 << 16)

// ================= all-RMW comm primitives (XCD-0 pinned, r7-proven) =======
// Every cross-CU transfer is a RETURNING atomic (sc0) executing at the XCD-0
// TCC; the s_waitcnt vmcnt(0) waits for the returned value => the RMW has
// EXECUTED in L2 (not merely queued). Atomics never hit L1 -> never stale.
__device__ __forceinline__ void st_atomic_f(float* p, float v) {
  int old;
  asm volatile("global_atomic_swap %0, %1, %2, off sc0\n\ts_waitcnt vmcnt(0)"
               : "=&v"(old) : "v"(p), "v"(__float_as_int(v)) : "memory");
}
// two swaps, one drain; returns stay live inside the asm block (no compiler
// register-reuse hazard on the pending return values).
__device__ __forceinline__ void st_atomic_f2(float* p0, float v0, float* p1, float v1) {
  int o0, o1;
  asm volatile("global_atomic_swap %0, %2, %3, off sc0\n\t"
               "global_atomic_swap %1, %4, %5, off sc0\n\t"
               "s_waitcnt vmcnt(0)"
               : "=&v"(o0), "=&v"(o1)
               : "v"(p0), "v"(__float_as_int(v0)), "v"(p1), "v"(__float_as_int(v1))
               : "memory");
}
__device__ __forceinline__ float ld_atomic_f(const float* p) {
  int v;
  asm volatile("global_atomic_add %0, %1, %2, off sc0\n\ts_waitcnt vmcnt(0)"
               : "=&v"(v) : "v"(p), "v"(0) : "memory");
  return __int_as_float(v);
}
__device__ __forceinline__ void flag_store_atomic(int* p, int v) {
  int old;
  asm volatile("global_atomic_swap %0, %1, %2, off sc0\n\ts_waitcnt vmcnt(0)"
               : "=&v"(old) : "v"(p), "v"(v) : "memory");
}
__device__ __forceinline__ int flag_poll_atomic(int* p) {
  int v;
  asm volatile("global_atomic_add %0, %1, %2, off sc0\n\ts_waitcnt vmcnt(0)"
               : "=&v"(v) : "v"(p), "v"(0) : "memory");
  return v;
}
__device__ __forceinline__ void wait_flag_wave(int* p, int want, int lane) {
  int v = 0, n = 0;
  do {
    if (lane == 0) v = flag_poll_atomic(p);
    v = __shfl(v, 0, 64);
    if (v >= want) break;
  } while (++n <= SPIN_CAP);
}
__device__ __forceinline__ int wait_prev_wave(int* p, int want, int lane) {
  int v = 0, n = 0;
  do {
    if (lane == 0) v = flag_poll_atomic(p);
    v = __shfl(v, 0, 64);
    if ((v >> 16) >= want) break;
  } while (++n <= SPIN_CAP);
  return v & 0xffff;
}

// ---- single-chain dot macros: EXACT round-2/7 arithmetic (absmax 0.0 twice
// proven). DO NOT restructure the fma chains or add orders: the sampling
// comparison cumsum > s*total sits on 1-ulp knife edges.
#define DOTREG(N4, W, V4, ACC) do { \
  _Pragma("unroll") \
  for (int k_ = 0; k_ < (N4); ++k_) { float4 a_ = (V4)[k_]; \
    ACC = fmaf((W)[4*k_+0], a_.x, ACC); ACC = fmaf((W)[4*k_+1], a_.y, ACC); \
    ACC = fmaf((W)[4*k_+2], a_.z, ACC); ACC = fmaf((W)[4*k_+3], a_.w, ACC); } \
} while (0)

#define DOTREG_RELU(N4, W, V4, ACC) do { \
  _Pragma("unroll") \
  for (int k_ = 0; k_ < (N4); ++k_) { float4 a_ = (V4)[k_]; \
    a_.x = fmaxf(a_.x, 0.f); a_.y = fmaxf(a_.y, 0.f); \
    a_.z = fmaxf(a_.z, 0.f); a_.w = fmaxf(a_.w, 0.f); \
    ACC = fmaf((W)[4*k_+0], a_.x, ACC); ACC = fmaf((W)[4*k_+1], a_.y, ACC); \
    ACC = fmaf((W)[4*k_+2], a_.z, ACC); ACC = fmaf((W)[4*k_+3], a_.w, ACC); } \
} while (0)

__global__ void cond_prep_kernel(const float* __restrict__ condW,
                                 const float* __restrict__ y,
                                 float* __restrict__ cond8) {
  int idx = blockIdx.x * blockDim.x + threadIdx.x;
  if (idx >= FRAMES_ * L_ * G_) return;
  int f = idx / (L_ * G_);
  int row = idx - f * (L_ * G_);
  float acc = 0.f;
  for (int m = 0; m < MEL_; ++m)
    acc = fmaf(condW[row * MEL_ + m], y[m * FRAMES_ + f], acc);
  cond8[f * (L_ * G_) + row] = acc;
}

__global__ __launch_bounds__(256, 1) void wavenet_pipe(
    const float* __restrict__ samples,
    const int*   __restrict__ c_ptr,
    const float* __restrict__ emb,
    const float* __restrict__ WVp,
    const float* __restrict__ WVx,
    const float* __restrict__ Wo,
    const float* __restrict__ Wob,
    const float* __restrict__ Wol,
    const float* __restrict__ Wobl,
    const float* __restrict__ e1w,
    const float* __restrict__ e1b,
    const float* __restrict__ e2w,
    const float* __restrict__ e2b,
    float* __restrict__ ws,
    int*   __restrict__ out) {

  const int tid = threadIdx.x;

  float* cond8  = ws + COND8_OFF;
  float* hist   = ws + HIST_OFF;
  float* mbxs   = ws + MBX_OFF;
  float* mbsks  = ws + MBSK_OFF;
  float* mbskip = ws + MBSKIP_OFF;
  float* mbhid  = ws + MBHID_OFF;
  int*   flags  = (int*)(ws + FLAG_OFF);

  __shared__ __align__(16) float x_s[R_];
  __shared__ __align__(16) float xb_s[R_];
  __shared__ __align__(16) float h_s[G_];
  __shared__ __align__(16) float z_s[R_];
  __shared__ __align__(16) float pd_a[G_];
  __shared__ __align__(16) float pd_b[G_];
  __shared__ __align__(16) float past_a_s[R_];
  __shared__ __align__(16) float past_b_s[R_];
  __shared__ __align__(16) float sk_s[S_];
  __shared__ __align__(16) float cond_a_s[FRAMES_ * G_];
  __shared__ __align__(16) float cond_b_s[FRAMES_ * G_];  // D reuses as logits
  __shared__ __align__(16) float vec_s[S_];
  __shared__ float wred[4], wsum[4];
  __shared__ int wcand[4];
  __shared__ int role_s;

  // ---- XCD-pinned role claiming (r7-proven): blocks on XCD 0 claim roles.
  {
    unsigned xcc;
    asm volatile("s_getreg_b32 %0, hwreg(HW_REG_XCC_ID)" : "=s"(xcc));
    if (tid == 0) {
      int r = -1;
      if (xcc == 0) {
        int c0 = atomicAdd(flags + FID_CLAIM * 16, 1);
        if (c0 < NROLE) r = c0;
      }
      role_s = r;
    }
    __syncthreads();
  }
  const int bid = role_s;
  if (bid < 0) return;

  if (bid < 5) {
    // ============ B_k: layers j_a=2k, j_b=2k+1 ============
    const int k = bid;
    const int j_a = 2 * k, j_b = 2 * k + 1;
    const int dil_a = 1 << j_a, dil_b = 1 << j_b;
    const int row = tid >> 1, half = tid & 1;

    // ---- weights in VGPRs ----
    float wxa[32], wpa[32], wxb[32], wpb[32], woa0[64], wob0[64], wex[64];
    float ba0, bb0, bex = 0.f;
    {
      const float* p;
      p = WVx + ((size_t)(j_a * G_ + row)) * R_ + half * 32;
      #pragma unroll
      for (int i = 0; i < 32; ++i) wxa[i] = p[i];
      p = WVp + ((size_t)(j_a * G_ + row)) * R_ + half * 32;
      #pragma unroll
      for (int i = 0; i < 32; ++i) wpa[i] = p[i];
      p = WVx + ((size_t)(j_b * G_ + row)) * R_ + half * 32;
      #pragma unroll
      for (int i = 0; i < 32; ++i) wxb[i] = p[i];
      if (k < 4) {
        p = WVp + ((size_t)(j_b * G_ + row)) * R_ + half * 32;
        #pragma unroll
        for (int i = 0; i < 32; ++i) wpb[i] = p[i];
      }
      p = Wo + ((size_t)(j_a * (R_ + S_) + tid)) * R_;
      #pragma unroll
      for (int i = 0; i < 64; ++i) woa0[i] = p[i];
      ba0 = Wob[j_a * (R_ + S_) + tid];
      if (k < 4) {
        p = Wo + ((size_t)(j_b * (R_ + S_) + tid)) * R_;
        #pragma unroll
        for (int i = 0; i < 64; ++i) wob0[i] = p[i];
        bb0 = Wob[j_b * (R_ + S_) + tid];
      } else {
        p = Wol + (size_t)tid * R_;
        #pragma unroll
        for (int i = 0; i < 64; ++i) wob0[i] = p[i];
        bb0 = Wobl[tid];
      }
      // shared "extra rows" array: tid<64 -> Wo_a rows 256+tid;
      // tid in [64,128) (k<4) -> Wo_b rows 256+(tid-64)
      if (tid < 64) {
        p = Wo + ((size_t)(j_a * (R_ + S_) + 256 + tid)) * R_;
        #pragma unroll
        for (int i = 0; i < 64; ++i) wex[i] = p[i];
        bex = Wob[j_a * (R_ + S_) + 256 + tid];
      } else if (tid < 128 && k < 4) {
        p = Wo + ((size_t)(j_b * (R_ + S_) + 256 + (tid - 64))) * R_;
        #pragma unroll
        for (int i = 0; i < 64; ++i) wex[i] = p[i];
        bex = Wob[j_b * (R_ + S_) + 256 + (tid - 64)];
      }
    }
    for (int i = tid; i < FRAMES_ * G_; i += 256) {
      cond_a_s[i] = cond8[(i >> 7) * (L_ * G_) + j_a * G_ + (i & 127)];
      cond_b_s[i] = cond8[(i >> 7) * (L_ * G_) + j_b * G_ + (i & 127)];
    }
    __syncthreads();
    if (tid < G_) { pd_a[tid] = cond_a_s[tid]; pd_b[tid] = cond_b_s[tid]; }

    const float* mbx_in  = mbxs + (size_t)(k - 1) * 64;    // valid k>=1
    const float* mbsk_in = mbsks + (size_t)(k - 1) * 256;
    float* mbx_out  = mbxs + (size_t)k * 64;               // valid k<4
    float* mbsk_out = mbsks + (size_t)k * 256;
    int* inflag   = flags + k * 16;                        // k>=1
    int* prevflag = flags + FID_PREV * 16;
    int* outflag  = (k < 4) ? (flags + (k + 1) * 16) : (flags + FID_SKIP * 16);
    float* hist_a = (k > 0) ? (hist + (size_t)(j_a - 1) * T_ * R_) : nullptr;
    float* hist_b = (k < 4) ? (hist + (size_t)(j_b - 1) * T_ * R_) : nullptr;

    for (int t = 0; t < T_; ++t) {
      // A: acquire input x
      if (tid < 64) {
        if (k == 0) {
          int prev = 127;
          if (t > 0) prev = wait_prev_wave(prevflag, t, tid);
          if (tid < 16)
            ((float4*)x_s)[tid] = ((const float4*)(emb + (size_t)prev * R_))[tid];
        } else {
          wait_flag_wave(inflag, t + 1, tid);
          x_s[tid] = ld_atomic_f(mbx_in + tid);
        }
      }
      __syncthreads();  // (1)

      // B: gate layer a  (h = wx-chunks-reduced + pd_a)
      {
        float v = 0.f;
        const float4* xs4 = (const float4*)(x_s + half * 32);
        DOTREG(8, wxa, xs4, v);
        v += __shfl_down(v, 1, 2);
        if (half == 0) h_s[row] = v + pd_a[row];
      }
      if (hist_a && tid < 16)
        ((float4*)(hist_a + (size_t)t * R_))[tid] = ((const float4*)x_s)[tid];
      __syncthreads();  // (2)

      // C: z_a
      if (tid < 64) {
        float hw = h_s[tid], hf = h_s[tid + 64];
        z_s[tid] = tanhf(hw) * (1.f / (1.f + expf(-hf)));
      }
      __syncthreads();  // (3)

      // D: Wo layer a -> xb_s, sk_s  (same add orders as r7)
      {
        float skin = 0.f;
        if (k > 0) {
          if (tid >= 64) skin = ld_atomic_f(mbsk_in + (tid - 64));
          else           skin = ld_atomic_f(mbsk_in + 192 + tid);
        }
        float v0 = 0.f;
        const float4* z4 = (const float4*)z_s;
        DOTREG(16, woa0, z4, v0);
        if (tid < 64) {
          float v1 = 0.f;
          DOTREG(16, wex, z4, v1);
          xb_s[tid] = x_s[tid] + v0 + ba0;
          sk_s[192 + tid] = skin + v1 + bex;
        } else {
          sk_s[tid - 64] = skin + v0 + ba0;
        }
      }
      __syncthreads();  // (4)

      // E: gate layer b
      {
        float v = 0.f;
        const float4* xs4 = (const float4*)(xb_s + half * 32);
        DOTREG(8, wxb, xs4, v);
        v += __shfl_down(v, 1, 2);
        if (half == 0) h_s[row] = v + pd_b[row];
      }
      if (hist_b && tid < 16)
        ((float4*)(hist_b + (size_t)t * R_))[tid] = ((const float4*)xb_s)[tid];
      __syncthreads();  // (5)

      // F: z_b
      if (tid < 64) {
        float hw = h_s[tid], hf = h_s[tid + 64];
        z_s[tid] = tanhf(hw) * (1.f / (1.f + expf(-hf)));
      }
      __syncthreads();  // (6)

      // G: Wo layer b + publish
      {
        float v0 = 0.f;
        const float4* z4 = (const float4*)z_s;
        DOTREG(16, wob0, z4, v0);
        if (k < 4) {
          if (tid < 64) {
            st_atomic_f(mbx_out + tid, xb_s[tid] + v0 + bb0);
          } else if (tid < 128) {
            float v1 = 0.f;
            DOTREG(16, wex, z4, v1);
            st_atomic_f2(mbsk_out + (tid - 64), sk_s[tid - 64] + v0 + bb0,
                         mbsk_out + 128 + tid,  sk_s[128 + tid] + v1 + bex);
          } else {
            st_atomic_f(mbsk_out + (tid - 64), sk_s[tid - 64] + v0 + bb0);
          }
        } else {
          st_atomic_f(mbskip + tid, sk_s[tid] + v0 + bb0);
        }
      }
      __syncthreads();  // (7) every swap has EXECUTED at the TCC
      if (tid == 0) flag_store_atomic(outflag, t + 1);

      // H: off-critical-path: precompute pd_a/pd_b for t+1
      const int tn = t + 1;
      if (tn < T_) {
        const int f1 = tn >> 6;
        if (k > 0 && tid < 16) {
          const int tp = tn - dil_a;
          float4 pv = make_float4(0.f, 0.f, 0.f, 0.f);
          if (tp >= 0) pv = ((const float4*)(hist_a + (size_t)tp * R_))[tid];
          ((float4*)past_a_s)[tid] = pv;
        }
        if (k < 4 && tid >= 16 && tid < 32) {
          const int tp = tn - dil_b;
          float4 pv = make_float4(0.f, 0.f, 0.f, 0.f);
          if (tp >= 0) pv = ((const float4*)(hist_b + (size_t)tp * R_))[tid - 16];
          ((float4*)past_b_s)[tid - 16] = pv;
        }
        __syncthreads();  // (8)
        {
          float v = 0.f;
          const float4* ps4 = (k == 0) ? (const float4*)(x_s + half * 32)
                                       : (const float4*)(past_a_s + half * 32);
          DOTREG(8, wpa, ps4, v);
          v += __shfl_down(v, 1, 2);
          if (half == 0) pd_a[row] = v + cond_a_s[f1 * G_ + row];
        }
        if (k < 4) {
          float v = 0.f;
          const float4* ps4 = (const float4*)(past_b_s + half * 32);
          DOTREG(8, wpb, ps4, v);
          v += __shfl_down(v, 1, 2);
          if (half == 0) pd_b[row] = v + cond_b_s[f1 * G_ + row];
        } else {
          if (tid < G_) pd_b[tid] = cond_b_s[f1 * G_ + tid];  // layer 9: past always 0
        }
      }
      __syncthreads();  // (9) pd/x_s writes ordered before next-iter overwrite
    }

  } else if (bid == 5) {
    // ============ C: full E1 (256 rows) ============
    const int o_loc = tid >> 1, halfc = tid & 1;
    float w0[128], w1[128];
    {
      const float* p = e1w + ((size_t)o_loc) * S_ + halfc * 128;
      #pragma unroll
      for (int i = 0; i < 128; ++i) w0[i] = p[i];
      p = e1w + ((size_t)(128 + o_loc)) * S_ + halfc * 128;
      #pragma unroll
      for (int i = 0; i < 128; ++i) w1[i] = p[i];
    }
    const float bias0 = e1b[o_loc], bias1 = e1b[128 + o_loc];
    int* inflag  = flags + FID_SKIP * 16;
    int* outflag = flags + FID_HID * 16;

    for (int t = 0; t < T_; ++t) {
      if (tid < 64) wait_flag_wave(inflag, t + 1, tid);
      __syncthreads();
      vec_s[tid] = ld_atomic_f(mbskip + tid);
      __syncthreads();
      const float4* s4 = (const float4*)(vec_s + halfc * 128);
      float v0 = 0.f, v1 = 0.f;
      DOTREG_RELU(32, w0, s4, v0);
      v0 += __shfl_down(v0, 1, 2);
      DOTREG_RELU(32, w1, s4, v1);
      v1 += __shfl_down(v1, 1, 2);
      if (halfc == 0)
        st_atomic_f2(mbhid + o_loc,       fmaxf(v0 + bias0, 0.f),
                     mbhid + 128 + o_loc, fmaxf(v1 + bias1, 0.f));
      __syncthreads();
      if (tid == 0) flag_store_atomic(outflag, t + 1);
    }

  } else {
    // ============ D: full E2 + sampling ============
    const int o_loc = tid >> 1, halfc = tid & 1;
    const float cf = (float)c_ptr[0];
    float w0[128], w1[128];
    {
      const float* p = e2w + ((size_t)o_loc) * END_ + halfc * 128;
      #pragma unroll
      for (int i = 0; i < 128; ++i) w0[i] = p[i];
      p = e2w + ((size_t)(128 + o_loc)) * END_ + halfc * 128;
      #pragma unroll
      for (int i = 0; i < 128; ++i) w1[i] = p[i];
    }
    const float bias0 = e2b[o_loc], bias1 = e2b[128 + o_loc];
    int* inflag = flags + FID_HID * 16;
    int* fprev  = flags + FID_PREV * 16;
    float* logits_s = cond_b_s;  // reuse (unused by D)
    const int lane = tid & 63, wv = tid >> 6;

    for (int t = 0; t < T_; ++t) {
      if (tid < 64) wait_flag_wave(inflag, t + 1, tid);
      __syncthreads();
      vec_s[tid] = ld_atomic_f(mbhid + tid);
      __syncthreads();
      const float4* h4 = (const float4*)(vec_s + halfc * 128);
      float v0 = 0.f, v1 = 0.f;
      DOTREG(32, w0, h4, v0);
      v0 += __shfl_down(v0, 1, 2);
      DOTREG(32, w1, h4, v1);
      v1 += __shfl_down(v1, 1, 2);
      if (halfc == 0) {
        logits_s[o_loc]       = (v0 + bias0) * cf;
        logits_s[128 + o_loc] = (v1 + bias1) * cf;
      }
      __syncthreads();

      // ---- softmax-CDF sampling over 256 logits (r7-exact) ----
      float lg = logits_s[tid];
      float m = lg;
      #pragma unroll
      for (int off = 32; off >= 1; off >>= 1) m = fmaxf(m, __shfl_xor(m, off, 64));
      if (lane == 0) wred[wv] = m;
      __syncthreads();
      m = fmaxf(fmaxf(wred[0], wred[1]), fmaxf(wred[2], wred[3]));
      float e = expf(lg - m);
      float cs = e;
      #pragma unroll
      for (int off = 1; off < 64; off <<= 1) {
        float o_ = __shfl_up(cs, off, 64);
        if (lane >= off) cs += o_;
      }
      if (lane == 63) wsum[wv] = cs;
      __syncthreads();
      float total = wsum[0] + wsum[1] + wsum[2] + wsum[3];
      float offv = 0.f;
      for (int w2 = 0; w2 < wv; ++w2) offv += wsum[w2];
      float thresh = samples[t] * total;
      bool flagb = (offv + cs) > thresh;
      unsigned long long mk = __ballot(flagb);
      if (lane == 0) wcand[wv] = mk ? (wv * 64 + __ffsll(mk) - 1) : 100000;
      __syncthreads();
      if (tid == 0) {
        int nw = min(min(wcand[0], wcand[1]), min(wcand[2], wcand[3]));
        if (nw >= 100000) nw = 0;  // argmax of all-False -> 0
        out[t] = nw;
        flag_store_atomic(fprev, ((t + 1) << 16) | nw);
      }
      __syncthreads();  // protect wred/wsum/logits_s before next step
    }
  }
}

extern "C" void kernel_launch(void* const* d_in, const int* in_sizes, int n_in,
                              void* d_out, int out_size, void* d_ws, size_t ws_size,
                              hipStream_t stream) {
  const float* y       = (const float*)d_in[0];
  const float* samples = (const float*)d_in[1];
  const int*   c       = (const int*)d_in[2];
  const float* emb     = (const float*)d_in[3];
  const float* condW   = (const float*)d_in[4];
  const float* WVp     = (const float*)d_in[5];
  const float* WVx     = (const float*)d_in[6];
  const float* Wo      = (const float*)d_in[7];
  const float* Wob     = (const float*)d_in[8];
  const float* Wol     = (const float*)d_in[9];
  const float* Wobl    = (const float*)d_in[10];
  const float* e1w     = (const float*)d_in[11];
  const float* e1b     = (const float*)d_in[12];
  const float* e2w     = (const float*)d_in[13];
  const float* e2b     = (const float*)d_in[14];

  float* ws  = (float*)d_ws;
  int*   out = (int*)d_out;

  // flags + claim counter must start at 0 every launch (ws re-poisoned to 0xAA)
  hipMemsetAsync((char*)d_ws + (size_t)FLAG_OFF * sizeof(float), 0,
                 16 * 16 * sizeof(int), stream);

  cond_prep_kernel<<<(FRAMES_ * L_ * G_ + 255) / 256, 256, 0, stream>>>(
      condW, y, ws + COND8_OFF);

  wavenet_pipe<<<256, 256, 0, stream>>>(samples, c, emb, WVp, WVx, Wo, Wob,
                                        Wol, Wobl, e1w, e1b, e2w, e2b, ws, out);
}